// Round 7
// baseline (62.529 us; speedup 1.0000x reference)
//
#include <hip/hip_runtime.h>
#include <hip/hip_bf16.h>

// FilterBank via bf16 MFMA, swapped operands:
//   D[t_row, band_col] = sum_k A[t,k] B[k,band],  A[i,k] = xpad[t0+i+k+2],
//   B[k,n] = W[n,k]  (xpad[i] = x[i-64], zero outside [0,1000))
// C/D layout: col = lane&15 = band n, row = 4*(lane>>4)+reg = t -> each lane's
// 4 acc regs are 4 CONSECUTIVE t of one band.
// Round 7: dual independent MFMA chains (tile pairs share the 8-slot F ring:
// 2 ds_read_b128 feed 8 MFMAs) + per-wave LDS transpose epilogue: 1
// ds_write_b128 per tile, flush every 64 t as 256B-contiguous f32x4 stores.
// LDS 28.4KB -> 5 blocks/CU. Fused taps, single launch.

#define T_LEN    1000
#define NB       9
#define S_COPY   1160      // elements per shifted copy (multiple of 8)
#define SLOTS    145       // 16B slots (8 elems) per copy
#define STG_W    68        // floats per band row in stg (16B-aligned stride)

typedef __attribute__((ext_vector_type(8))) short short8;
typedef __attribute__((ext_vector_type(4))) float f32x4;

__device__ __forceinline__ unsigned int f2bf(float f) {
    union { __hip_bfloat16 h; unsigned short u; } cv;
    cv.h = __float2bfloat16(f);
    return (unsigned int)cv.u;
}

__global__ __launch_bounds__(256) void fbank_mfma(
    const float* __restrict__ x,
    const float* __restrict__ kern,
    float* __restrict__ out)
{
    __shared__ unsigned short xs[8 * S_COPY];    // 18560 B
    __shared__ float stg[4 * NB * STG_W];        // 9792 B, per-wave [9][68]

    const int tid = threadIdx.x;
    const int bc  = blockIdx.x;                  // b*64 + c
    const int b   = bc >> 6, c = bc & 63;
    const float* xrow = x + (size_t)bc * T_LEN;

    // ---- stage 8 shifted bf16 copies: copy r, slot q = xpad[8q+r .. +7] ----
    {
        const int r = tid >> 5, q0 = tid & 31;
        #pragma unroll
        for (int i = 0; i < 5; ++i) {
            int q = q0 + 32 * i;
            if (q < SLOTS) {
                int idx0 = 8 * q + r - 64;       // x-index of element 0
                unsigned int d[4];
                #pragma unroll
                for (int e2 = 0; e2 < 4; ++e2) {
                    int i0 = idx0 + 2 * e2, i1 = i0 + 1;
                    float v0 = ((unsigned)i0 < T_LEN) ? xrow[i0] : 0.f;
                    float v1 = ((unsigned)i1 < T_LEN) ? xrow[i1] : 0.f;
                    d[e2] = f2bf(v0) | (f2bf(v1) << 16);
                }
                *reinterpret_cast<uint4*>(&xs[r * S_COPY + 8 * q]) =
                    make_uint4(d[0], d[1], d[2], d[3]);
            }
        }
    }

    const int lane = tid & 63;
    const int wid  = tid >> 6;
    const int n = lane & 15, g = lane >> 4;      // n = band col, g = k/row group

    // ---- B frags (taps) from global kern, loop-invariant ----
    short8 bt[4];
    #pragma unroll
    for (int kk = 0; kk < 4; ++kk) {
        unsigned int u[4];
        #pragma unroll
        for (int e2 = 0; e2 < 4; ++e2) {
            int k0 = kk * 32 + 8 * g + 2 * e2;
            float v0 = (n < NB && k0 < 125)     ? kern[n * 125 + k0]     : 0.f;
            float v1 = (n < NB && k0 + 1 < 125) ? kern[n * 125 + k0 + 1] : 0.f;
            u[e2] = f2bf(v0) | (f2bf(v1) << 16);
        }
        union { uint4 u4; short8 s8; } cv;
        cv.u4 = make_uint4(u[0], u[1], u[2], u[3]);
        bt[kk] = cv.s8;
    }

    __syncthreads();

    const int t0w = wid << 8;                    // wave owns t in [256w, 256w+256)
    const int rl  = (n + 2) & 7;                 // A-row i = n : alignment class
    const char* xsb = reinterpret_cast<const char*>(xs);
    // F[u] element index s = t0w + 2 + n + 8g + 16u, LDS elem = 1159*rl + s
    const int LB = 2 * (1159 * rl + 2 + n + 8 * g + t0w);

    float* sw = stg + wid * (NB * STG_W);        // this wave's staging buffer
    const bool bandok = (n < NB);

    short8 F[8];
    #pragma unroll
    for (int u = 0; u < 6; ++u)
        F[u] = *reinterpret_cast<const short8*>(xsb + LB + 32 * u);

    #pragma unroll
    for (int ch = 0; ch < 4; ++ch) {             // 64-t chunks
        #pragma unroll
        for (int pp = 0; pp < 2; ++pp) {         // tile pairs within chunk
            const int P = ch * 2 + pp;           // pair: tiles 2P, 2P+1
            F[(2 * P + 6) & 7] = *reinterpret_cast<const short8*>(xsb + LB + 32 * (2 * P + 6));
            F[(2 * P + 7) & 7] = *reinterpret_cast<const short8*>(xsb + LB + 32 * (2 * P + 7));
            f32x4 ae = {0.f, 0.f, 0.f, 0.f}, ao = {0.f, 0.f, 0.f, 0.f};
            #pragma unroll
            for (int kk = 0; kk < 4; ++kk) {
                ae = __builtin_amdgcn_mfma_f32_16x16x32_bf16(F[(2 * P + 2 * kk) & 7],     bt[kk], ae, 0, 0, 0);
                ao = __builtin_amdgcn_mfma_f32_16x16x32_bf16(F[(2 * P + 1 + 2 * kk) & 7], bt[kk], ao, 0, 0, 0);
            }
            if (bandok) {
                const int base = n * STG_W + 32 * pp + 4 * g;
                *reinterpret_cast<f32x4*>(sw + base)      = ae;   // tile 2P
                *reinterpret_cast<f32x4*>(sw + base + 16) = ao;   // tile 2P+1
            }
        }
        // flush chunk: 9 bands x 64 contiguous t, 256B segments per instr
        const int tcb = t0w + 64 * ch;
        #pragma unroll
        for (int it = 0; it < 3; ++it) {
            int flat = it * 64 + lane;           // 0..191 (need < 144)
            int bb = flat >> 4, cc = flat & 15;
            if (bb < NB && tcb + 4 * cc + 4 <= T_LEN) {
                f32x4 v = *reinterpret_cast<const f32x4*>(sw + bb * STG_W + 4 * cc);
                *reinterpret_cast<f32x4*>(
                    out + ((size_t)(b * NB + bb) * 64 + c) * T_LEN + tcb + 4 * cc) = v;
            }
        }
    }
}

extern "C" void kernel_launch(void* const* d_in, const int* in_sizes, int n_in,
                              void* d_out, int out_size, void* d_ws, size_t ws_size,
                              hipStream_t stream) {
    const float* x    = (const float*)d_in[0];
    const float* kern = (const float*)d_in[1];
    float* out = (float*)d_out;

    fbank_mfma<<<64 * 64, 256, 0, stream>>>(x, kern, out);
}

// Round 8
// 62.205 us; speedup vs baseline: 1.0052x; 1.0052x over previous
//
#include <hip/hip_runtime.h>
#include <hip/hip_bf16.h>

// FilterBank via bf16 MFMA, swapped operands:
//   D[t_row, band_col] = sum_k A[t,k] B[k,band],  A[i,k] = xpad[t0+i+k+2],
//   B[k,n] = W[n,k]  (xpad[i] = x[i-64], zero outside [0,1000))
// C/D layout: col = lane&15 = band n, row = 4*(lane>>4)+reg = t -> lane's 4
// acc regs are 4 CONSECUTIVE t of one band.
// Round 8: persistent accumulators (16 independent MFMA chains, no stores in
// loop) + xs-LDS reused as transpose buffer after compute + 4 serialized
// per-wave flush rounds, each emitting 9 x 1KB fully-coalesced stores
// (one band x 256 t per instruction) -> long-run write streams, few
// concurrent streams (fill-kernel-like pattern).

#define T_LEN    1000
#define NB       9
#define S_COPY   1160      // elements per shifted copy (multiple of 8)
#define SLOTS    145       // 16B slots (8 elems) per copy
#define STG_W    264       // f32 per band row in flush buffer (264%32=8)

typedef __attribute__((ext_vector_type(8))) short short8;
typedef __attribute__((ext_vector_type(4))) float f32x4;

__device__ __forceinline__ unsigned int f2bf(float f) {
    union { __hip_bfloat16 h; unsigned short u; } cv;
    cv.h = __float2bfloat16(f);
    return (unsigned int)cv.u;
}

__global__ __launch_bounds__(256) void fbank_mfma(
    const float* __restrict__ x,
    const float* __restrict__ kern,
    float* __restrict__ out)
{
    __shared__ unsigned short xs[8 * S_COPY];    // 18560 B; reused as 9x264 f32 flush buf

    const int tid = threadIdx.x;
    const int bc  = blockIdx.x;                  // b*64 + c
    const int b   = bc >> 6, c = bc & 63;
    const float* xrow = x + (size_t)bc * T_LEN;

    // ---- stage 8 shifted bf16 copies: copy r, slot q = xpad[8q+r .. +7] ----
    {
        const int r = tid >> 5, q0 = tid & 31;
        #pragma unroll
        for (int i = 0; i < 5; ++i) {
            int q = q0 + 32 * i;
            if (q < SLOTS) {
                int idx0 = 8 * q + r - 64;       // x-index of element 0
                unsigned int d[4];
                #pragma unroll
                for (int e2 = 0; e2 < 4; ++e2) {
                    int i0 = idx0 + 2 * e2, i1 = i0 + 1;
                    float v0 = ((unsigned)i0 < T_LEN) ? xrow[i0] : 0.f;
                    float v1 = ((unsigned)i1 < T_LEN) ? xrow[i1] : 0.f;
                    d[e2] = f2bf(v0) | (f2bf(v1) << 16);
                }
                *reinterpret_cast<uint4*>(&xs[r * S_COPY + 8 * q]) =
                    make_uint4(d[0], d[1], d[2], d[3]);
            }
        }
    }

    const int lane = tid & 63;
    const int wid  = tid >> 6;
    const int n = lane & 15, g = lane >> 4;      // n = band col, g = k/row group

    // ---- B frags (taps) from global kern, loop-invariant ----
    short8 bt[4];
    #pragma unroll
    for (int kk = 0; kk < 4; ++kk) {
        unsigned int u[4];
        #pragma unroll
        for (int e2 = 0; e2 < 4; ++e2) {
            int k0 = kk * 32 + 8 * g + 2 * e2;
            float v0 = (n < NB && k0 < 125)     ? kern[n * 125 + k0]     : 0.f;
            float v1 = (n < NB && k0 + 1 < 125) ? kern[n * 125 + k0 + 1] : 0.f;
            u[e2] = f2bf(v0) | (f2bf(v1) << 16);
        }
        union { uint4 u4; short8 s8; } cv;
        cv.u4 = make_uint4(u[0], u[1], u[2], u[3]);
        bt[kk] = cv.s8;
    }

    __syncthreads();

    const int t0w = wid << 8;                    // wave owns t in [256w, 256w+256)
    const int rl  = (n + 2) & 7;                 // A-row i = n : alignment class
    const char* xsb = reinterpret_cast<const char*>(xs);
    // F[u] element index s = t0w + 2 + n + 8g + 16u, LDS elem = 1159*rl + s
    const int LB = 2 * (1159 * rl + 2 + n + 8 * g + t0w);

    short8 F[8];
    #pragma unroll
    for (int u = 0; u < 6; ++u)
        F[u] = *reinterpret_cast<const short8*>(xsb + LB + 32 * u);

    // ---- compute: 16 persistent acc chains, no stores ----
    f32x4 acc[16];
    #pragma unroll
    for (int m = 0; m < 16; ++m) {               // 16-t tile per iter
        F[(m + 6) & 7] = *reinterpret_cast<const short8*>(xsb + LB + 32 * (m + 6));
        f32x4 a = {0.f, 0.f, 0.f, 0.f};
        #pragma unroll
        for (int kk = 0; kk < 4; ++kk)
            a = __builtin_amdgcn_mfma_f32_16x16x32_bf16(F[(m + 2 * kk) & 7], bt[kk], a, 0, 0, 0);
        acc[m] = a;
    }

    // ---- flush: 4 serialized per-wave rounds through reused xs LDS ----
    float* stg = reinterpret_cast<float*>(xs);   // 9 x STG_W f32 = 9504 B
    for (int w = 0; w < 4; ++w) {
        __syncthreads();                         // stg free (prev round done / xs dead)
        if (wid == w) {
            if (n < NB) {
                #pragma unroll
                for (int m = 0; m < 16; ++m)
                    *reinterpret_cast<f32x4*>(stg + n * STG_W + 16 * m + 4 * g) = acc[m];
            }
            const int tl = 4 * lane;             // 0..252
            const bool ok = (t0w + tl + 4 <= T_LEN);
            #pragma unroll
            for (int i = 0; i < NB; ++i) {       // 9 x 1KB coalesced stores
                f32x4 v = *reinterpret_cast<const f32x4*>(stg + i * STG_W + tl);
                if (ok)
                    *reinterpret_cast<f32x4*>(
                        out + ((size_t)(b * NB + i) * 64 + c) * T_LEN + t0w + tl) = v;
            }
        }
    }
}

extern "C" void kernel_launch(void* const* d_in, const int* in_sizes, int n_in,
                              void* d_out, int out_size, void* d_ws, size_t ws_size,
                              hipStream_t stream) {
    const float* x    = (const float*)d_in[0];
    const float* kern = (const float*)d_in[1];
    float* out = (float*)d_out;

    fbank_mfma<<<64 * 64, 256, 0, stream>>>(x, kern, out);
}

// Round 9
// 56.203 us; speedup vs baseline: 1.1126x; 1.1068x over previous
//
#include <hip/hip_runtime.h>
#include <hip/hip_bf16.h>

// FilterBank via bf16 MFMA, swapped operands:
//   D[t_row, band_col] = sum_k A[t,k] B[k,band],  A[i,k] = xpad[t0+i+k+2],
//   B[k,n] = W[n,k]  (xpad[i] = x[i-64], zero outside [0,1000))
// C/D layout: col = lane&15 = band n, row = 4*(lane>>4)+reg = t -> lane's 4
// acc regs are 4 CONSECUTIVE t of one band.
// Round 9:
//  - prep_taps kernel restored (r3/r4, the fast cluster): tap frags load as
//    4 clean aligned short8 from d_ws instead of 32 guarded scalar loads +
//    cvt per thread in every block's prologue.
//  - bijective XCD swizzle: bc = (bid&7)*512 + (bid>>3) -> each XCD's L2 owns
//    a contiguous 18MB output region (8 b-values x all c), shrinking the
//    instantaneous HBM write-footprint interleave 8x.
//  - r8 compute: persistent acc (16 indep MFMA chains), xs-LDS reused as
//    flush buffer, 4 serialized per-wave flush rounds of 9 x 1KB stores.

#define T_LEN    1000
#define NB       9
#define KP       128
#define S_COPY   1160      // elements per shifted copy (multiple of 8)
#define SLOTS    145       // 16B slots (8 elems) per copy
#define STG_W    264       // f32 per band row in flush buffer

typedef __attribute__((ext_vector_type(8))) short short8;
typedef __attribute__((ext_vector_type(4))) float f32x4;

__device__ __forceinline__ unsigned int f2bf(float f) {
    union { __hip_bfloat16 h; unsigned short u; } cv;
    cv.h = __float2bfloat16(f);
    return (unsigned int)cv.u;
}

__global__ __launch_bounds__(256) void prep_taps(const float* __restrict__ kern,
                                                 unsigned short* __restrict__ kwb) {
    const int t = threadIdx.x;
    #pragma unroll
    for (int i = 0; i < 8; ++i) {
        int idx = t + 256 * i;            // 0..2047 over [16][128]
        int band = idx >> 7, k = idx & 127;
        float v = (band < NB && k < 125) ? kern[band * 125 + k] : 0.f;
        kwb[idx] = (unsigned short)f2bf(v);
    }
}

__global__ __launch_bounds__(256) void fbank_mfma(
    const float* __restrict__ x,
    const unsigned short* __restrict__ kwb,
    float* __restrict__ out)
{
    __shared__ unsigned short xs[8 * S_COPY];    // 18560 B; reused as flush buf

    const int tid = threadIdx.x;
    const int bid = blockIdx.x;
    // XCD swizzle: dispatch round-robins bid across 8 XCDs; remap so each XCD
    // gets a CONTIGUOUS bc chunk (512 = 4096/8) -> contiguous 18MB out region.
    const int bc  = ((bid & 7) << 9) + (bid >> 3);
    const int b   = bc >> 6, c = bc & 63;
    const float* xrow = x + (size_t)bc * T_LEN;

    // ---- stage 8 shifted bf16 copies: copy r, slot q = xpad[8q+r .. +7] ----
    {
        const int r = tid >> 5, q0 = tid & 31;
        #pragma unroll
        for (int i = 0; i < 5; ++i) {
            int q = q0 + 32 * i;
            if (q < SLOTS) {
                int idx0 = 8 * q + r - 64;       // x-index of element 0
                unsigned int d[4];
                #pragma unroll
                for (int e2 = 0; e2 < 4; ++e2) {
                    int i0 = idx0 + 2 * e2, i1 = i0 + 1;
                    float v0 = ((unsigned)i0 < T_LEN) ? xrow[i0] : 0.f;
                    float v1 = ((unsigned)i1 < T_LEN) ? xrow[i1] : 0.f;
                    d[e2] = f2bf(v0) | (f2bf(v1) << 16);
                }
                *reinterpret_cast<uint4*>(&xs[r * S_COPY + 8 * q]) =
                    make_uint4(d[0], d[1], d[2], d[3]);
            }
        }
    }

    const int lane = tid & 63;
    const int wid  = tid >> 6;
    const int n = lane & 15, g = lane >> 4;      // n = band col, g = k/row group

    // ---- B frags (taps): clean aligned short8 loads from prepped kwb ----
    // B[k,n] = W[n,k]; lane (n,g) frag kk holds W[n, kk*32+8g .. +7]
    short8 bt[4];
    #pragma unroll
    for (int kk = 0; kk < 4; ++kk)
        bt[kk] = *reinterpret_cast<const short8*>(kwb + n * KP + kk * 32 + g * 8);

    __syncthreads();

    const int t0w = wid << 8;                    // wave owns t in [256w, 256w+256)
    const int rl  = (n + 2) & 7;                 // A-row i = n : alignment class
    const char* xsb = reinterpret_cast<const char*>(xs);
    // F[u] element index s = t0w + 2 + n + 8g + 16u, LDS elem = 1159*rl + s
    const int LB = 2 * (1159 * rl + 2 + n + 8 * g + t0w);

    short8 F[8];
    #pragma unroll
    for (int u = 0; u < 6; ++u)
        F[u] = *reinterpret_cast<const short8*>(xsb + LB + 32 * u);

    // ---- compute: 16 persistent acc chains, no stores ----
    f32x4 acc[16];
    #pragma unroll
    for (int m = 0; m < 16; ++m) {               // 16-t tile per iter
        F[(m + 6) & 7] = *reinterpret_cast<const short8*>(xsb + LB + 32 * (m + 6));
        f32x4 a = {0.f, 0.f, 0.f, 0.f};
        #pragma unroll
        for (int kk = 0; kk < 4; ++kk)
            a = __builtin_amdgcn_mfma_f32_16x16x32_bf16(F[(m + 2 * kk) & 7], bt[kk], a, 0, 0, 0);
        acc[m] = a;
    }

    // ---- flush: 4 serialized per-wave rounds through reused xs LDS ----
    float* stg = reinterpret_cast<float*>(xs);   // 9 x STG_W f32 = 9504 B
    for (int w = 0; w < 4; ++w) {
        __syncthreads();                         // stg free (prev round done / xs dead)
        if (wid == w) {
            if (n < NB) {
                #pragma unroll
                for (int m = 0; m < 16; ++m)
                    *reinterpret_cast<f32x4*>(stg + n * STG_W + 16 * m + 4 * g) = acc[m];
            }
            const int tl = 4 * lane;             // 0..252
            const bool ok = (t0w + tl + 4 <= T_LEN);
            #pragma unroll
            for (int i = 0; i < NB; ++i) {       // 9 x 1KB coalesced stores
                f32x4 v = *reinterpret_cast<const f32x4*>(stg + i * STG_W + tl);
                if (ok)
                    *reinterpret_cast<f32x4*>(
                        out + ((size_t)(b * NB + i) * 64 + c) * T_LEN + t0w + tl) = v;
            }
        }
    }
}

extern "C" void kernel_launch(void* const* d_in, const int* in_sizes, int n_in,
                              void* d_out, int out_size, void* d_ws, size_t ws_size,
                              hipStream_t stream) {
    const float* x    = (const float*)d_in[0];
    const float* kern = (const float*)d_in[1];
    float* out = (float*)d_out;
    unsigned short* kwb = (unsigned short*)d_ws;   // (16,128) bf16 padded taps

    prep_taps<<<1, 256, 0, stream>>>(kern, kwb);
    fbank_mfma<<<64 * 64, 256, 0, stream>>>(x, kwb, out);
}